// Round 9
// baseline (37.174 us; speedup 1.0000x reference)
//
#include <hip/hip_runtime.h>

constexpr int GRID_SZ = 5;
constexpr int N_CTRL  = 25;
constexpr int IMG_H   = 256;
constexpr int IMG_W   = 192;
constexpr int BATCH   = 64;
constexpr int BCHUNK  = 4;    // batches per block; ALL prefetched (depth-4 MLP)
constexpr int PLANE   = IMG_H * IMG_W;
constexpr int PIX_BLOCKS = PLANE / 256;             // 192
constexpr int NWG = PIX_BLOCKS * (BATCH / BCHUNK);  // 3072, divisible by 8
constexpr float RBF_SCALE = 10.0f;
constexpr float OFF_SCALE = 0.3f;

__global__ __launch_bounds__(256) void tps_warp_kernel(
    const float* __restrict__ cloth,   // (64,3,256,192)
    const float* __restrict__ theta,   // (64,50)
    float* __restrict__ out)           // (64,3,256,192)
{
    // XCD-contiguous swizzle (keeps HBM FETCH at compulsory ~17 MB).
    const int flat = blockIdx.x;
    const int wg   = (flat & 7) * (NWG / 8) + (flat >> 3);
    const int pb   = wg % PIX_BLOCKS;
    const int bc   = wg / PIX_BLOCKS;
    const int b0   = bc * BCHUNK;

    const int pix = pb * 256 + threadIdx.x;
    const int hh = pix / IMG_W;
    const int ww = pix - hh * IMG_W;
    const float mx = -1.0f + (2.0f / (IMG_W - 1)) * (float)ww;
    const float my = -1.0f + (2.0f / (IMG_H - 1)) * (float)hh;

    // separable RBF basis: 10 exps + 25 muls; OFF_SCALE folded in.
    float ex[GRID_SZ], ey[GRID_SZ];
#pragma unroll
    for (int k = 0; k < GRID_SZ; ++k) {
        const float c = -0.9f + 0.45f * (float)k;
        const float dx = mx - c;
        const float dy = my - c;
        ex[k] = __expf(-dx * dx * RBF_SCALE);
        ey[k] = __expf(-dy * dy * RBF_SCALE);
    }
    float wgt[N_CTRL];
#pragma unroll
    for (int n = 0; n < N_CTRL; ++n)
        wgt[n] = OFF_SCALE * ex[n % GRID_SZ] * ey[n / GRID_SZ];

    // ---- phase A: sample coords per batch (theta via SGPR s_loads, no LDS)
    float sxp[BCHUNK], syp[BCHUNK];
#pragma unroll
    for (int bi = 0; bi < BCHUNK; ++bi) {
        const float* __restrict__ th = theta + (size_t)(b0 + bi) * (2 * N_CTRL);
        float ox = 0.0f, oy = 0.0f;
#pragma unroll
        for (int n = 0; n < N_CTRL; ++n) {
            ox = fmaf(th[2 * n + 0], wgt[n], ox);
            oy = fmaf(th[2 * n + 1], wgt[n], oy);
        }
        const float gx = fminf(fmaxf(mx + ox, -1.0f), 1.0f);
        const float gy = fminf(fmaxf(my + oy, -1.0f), 1.0f);
        sxp[bi] = (gx + 1.0f) * (0.5f * (float)(IMG_W - 1));  // in [0, W-1]
        syp[bi] = (gy + 1.0f) * (0.5f * (float)(IMG_H - 1));  // in [0, H-1]
    }

    const size_t img_stride = (size_t)3 * PLANE;
    const float* imgb = cloth + (size_t)b0 * img_stride;
    float*       outb = out   + (size_t)b0 * img_stride + pix;

    // ---- phase B: issue ALL 24 gather loads, then PIN their results.
    // R8 lesson: sched_barrier alone does not stop IR-level load sinking
    // (VGPR stayed 36 < the 48 floats of v[]); a load cannot sink past a
    // USE of its result, so an empty asm with "+v" per value anchors every
    // load above this point -> true depth-24 MLP, counted vmcnt waits.
    float2 v[BCHUNK][6];     // [batch][ch*2 + row] — all statically indexed
#pragma unroll
    for (int bi = 0; bi < BCHUNK; ++bi) {
        const int x0 = min((int)sxp[bi], IMG_W - 2);
        const int y0 = min((int)syp[bi], IMG_H - 2);
        const int base = y0 * IMG_W + x0;
        const float* img = imgb + (size_t)bi * img_stride;
#pragma unroll
        for (int ch = 0; ch < 3; ++ch) {
            const float* pc = img + ch * PLANE + base;
            v[bi][ch * 2 + 0] = *reinterpret_cast<const float2*>(pc);
            v[bi][ch * 2 + 1] = *reinterpret_cast<const float2*>(pc + IMG_W);
        }
    }
#pragma unroll
    for (int bi = 0; bi < BCHUNK; ++bi)
#pragma unroll
        for (int k = 0; k < 6; ++k)
            asm volatile("" : "+v"(v[bi][k].x), "+v"(v[bi][k].y));
    __builtin_amdgcn_sched_barrier(0);

    // ---- phase C: blend all batches into registers
    float res[BCHUNK][3];
#pragma unroll
    for (int bi = 0; bi < BCHUNK; ++bi) {
        const float x = sxp[bi];
        const float y = syp[bi];
        const float wx = x - (float)min((int)x, IMG_W - 2);
        const float wy = y - (float)min((int)y, IMG_H - 2);
#pragma unroll
        for (int ch = 0; ch < 3; ++ch) {
            const float2 r0 = v[bi][ch * 2 + 0];
            const float2 r1 = v[bi][ch * 2 + 1];
            const float top = fmaf(wx, r0.y - r0.x, r0.x);
            const float bot = fmaf(wx, r1.y - r1.x, r1.x);
            res[bi][ch]     = fmaf(wy, bot - top, top);
        }
    }

    // ---- phase D: all stores at the end (nothing waits on them; NT keeps
    // 37 MB of write traffic out of the L2).
#pragma unroll
    for (int bi = 0; bi < BCHUNK; ++bi) {
        float* op = outb + (size_t)bi * img_stride;
#pragma unroll
        for (int ch = 0; ch < 3; ++ch)
            __builtin_nontemporal_store(res[bi][ch], op + ch * PLANE);
    }
}

extern "C" void kernel_launch(void* const* d_in, const int* in_sizes, int n_in,
                              void* d_out, int out_size, void* d_ws, size_t ws_size,
                              hipStream_t stream) {
    const float* cloth = (const float*)d_in[0];
    const float* theta = (const float*)d_in[1];
    float* out = (float*)d_out;

    tps_warp_kernel<<<dim3(NWG), dim3(256), 0, stream>>>(cloth, theta, out);
}